// Round 6
// baseline (272.539 us; speedup 1.0000x reference)
//
#include <hip/hip_runtime.h>

#define ANG 9
#define OHW 48
#define IMG 432
#define CIN 64
#define COUT 64
#define ND 9
#define NB 4
#define NVIEW 81
#define NSPAT 2304   // 48*48
#define NTOT 9216    // NB*NSPAT

#define SLABW 81                 // padded gather slab row stride (dwords)
#define SLABSZ (80 * SLABW)      // 6480 floats per var-slab

#define LXW 68                   // padded fused LDS row stride (u16): 136 B -> bank = 2*iw + ci/2

using f32x4 = __attribute__((ext_vector_type(4))) float;
using s16x8 = __attribute__((ext_vector_type(8))) short;
using s16x4 = __attribute__((ext_vector_type(4))) short;

__device__ __forceinline__ unsigned short f2bf(float f) {
    unsigned u = __float_as_uint(f);
    unsigned r = (u + 0x7FFFu + ((u >> 16) & 1u)) >> 16;   // RNE
    return (unsigned short)r;
}

// ---------------- kernel 1: pack W -> Aw[81][128][64] bf16 -------------------
// Aw[uv][co][ci]      = W[co][ci][u][v]          (var0, for d<=0)
// Aw[uv][64+co][ci]   = W[co][ci][8-u][8-v]      (var1, for d>0)
__global__ void k_wpack(const float* __restrict__ w, unsigned short* __restrict__ aw) {
    int idx = blockIdx.x * 256 + threadIdx.x;
    if (idx >= NVIEW * 128 * 64) return;
    int ci = idx & 63;
    int m  = (idx >> 6) & 127;
    int uv = idx >> 13;
    int u = uv / 9, v = uv % 9;
    int co = m & 63, var = m >> 6;
    int uu = var ? 8 - u : u;
    int vv = var ? 8 - v : v;
    aw[idx] = f2bf(w[((size_t)(co * 64 + ci) * 9 + uu) * 9 + vv]);
}

// ---------------- kernel 2: fused pack + per-view GEMM (v3) ------------------
// Block (h, u, b): stage x[b][:][9h+u][:] as bf16 LDS [iw][ci] with PAD-68 row
// stride (conflict-free b64 writes AND b64 frag reads, no swizzle).
// Staging: lane<->iw, 4 ci-plane dword loads -> 1 ds_write_b64.
// Compute: wave owns (mh,mf) 16-row m-tile; 27 unrolled v*nt bodies.
__global__ __launch_bounds__(512, 4)
void k_fused(const float* __restrict__ x,
             const unsigned short* __restrict__ aw,
             unsigned short* __restrict__ y) {
    __shared__ unsigned short lx[IMG * LXW];   // 58,752 B
    const int h = blockIdx.x, u = blockIdx.y, b = blockIdx.z;
    const int t = threadIdx.x;
    const int ih = 9 * h + u;
    const int lane = t & 63, wave = t >> 6;
    const int lr = lane & 15;   // n/m row selector
    const int lh = lane >> 4;   // k-group selector
    const int mh = wave >> 2;   // co-variant half
    const int mf = wave & 3;    // 16-row tile within the half

    // ---- A-preload a0 (k 0..31 slice), overlaps staging ----
    const unsigned short* abase =
        aw + (((size_t)(u * 9) * 128) + mh * 64 + mf * 16 + lr) * 64 + lh * 8;
    s16x8 a0[9];
#pragma unroll
    for (int v = 0; v < 9; ++v)
        a0[v] = *reinterpret_cast<const s16x8*>(abase + (size_t)v * 128 * 64);

    // ---- stage: 112 wave-tasks = 16 ci-groups x 7 iw-chunks ----
    {
        const size_t xrow = ((size_t)b * 64) * (IMG * IMG) + (size_t)ih * IMG;
        for (int task = wave; task < 112; task += 8) {
            const int cg = task / 7;           // ci-group: ci0 = 4*cg
            const int ch = task % 7;           // iw chunk of 64
            const int iw = ch * 64 + lane;
            if (iw < IMG) {
                const float* p = x + xrow + (size_t)(cg * 4) * (IMG * IMG) + iw;
                const float f0 = p[0];
                const float f1 = p[(size_t)(IMG * IMG)];
                const float f2 = p[(size_t)(2 * IMG * IMG)];
                const float f3 = p[(size_t)(3 * IMG * IMG)];
                const unsigned long long pk =
                      (unsigned long long)f2bf(f0)
                    | ((unsigned long long)f2bf(f1) << 16)
                    | ((unsigned long long)f2bf(f2) << 32)
                    | ((unsigned long long)f2bf(f3) << 48);
                reinterpret_cast<unsigned long long*>(lx)[iw * (LXW / 4) + cg] = pk;
            }
        }
    }
    __syncthreads();

    // ---- compute: 27 fully-unrolled independent tile bodies ----
    const s16x4* lx4 = reinterpret_cast<const s16x4*>(lx);   // 8B units, row = 17

    s16x8 a1n = *reinterpret_cast<const s16x8*>(abase + 32);   // v=0, k 32..63 slice
#pragma unroll
    for (int v = 0; v < 9; ++v) {
        const int uv = u * 9 + v;
        const s16x8 a1 = a1n;
        if (v < 8)
            a1n = *reinterpret_cast<const s16x8*>(abase + (size_t)(v + 1) * 128 * 64 + 32);
#pragma unroll
        for (int nt = 0; nt < 3; ++nt) {
            const int iw = 9 * (nt * 16 + lr) + v;
            const int r0 = iw * (LXW / 4) + 2 * lh;
            const s16x4 p0 = lx4[r0];
            const s16x4 p1 = lx4[r0 + 1];
            const s16x4 p2 = lx4[r0 + 8];
            const s16x4 p3 = lx4[r0 + 9];
            const s16x8 b0 = __builtin_shufflevector(p0, p1, 0, 1, 2, 3, 4, 5, 6, 7);
            const s16x8 b1 = __builtin_shufflevector(p2, p3, 0, 1, 2, 3, 4, 5, 6, 7);

            f32x4 acc = (f32x4){0.f, 0.f, 0.f, 0.f};
            acc = __builtin_amdgcn_mfma_f32_16x16x32_bf16(a0[v], b0, acc, 0, 0, 0);
            acc = __builtin_amdgcn_mfma_f32_16x16x32_bf16(a1,    b1, acc, 0, 0, 0);

            // D layout: col = lane&15, row = (lane>>4)*4 + reg  [m89-verified]
            const int n0 = b * NSPAT + h * 48 + nt * 16;
#pragma unroll
            for (int rr = 0; rr < 4; ++rr) {
                const int m = mh * 64 + mf * 16 + lh * 4 + rr;
                y[((size_t)uv * 128 + m) * NTOT + n0 + lr] = f2bf(acc[rr]);
            }
        }
    }
}

// ---------------- kernel 3: shift-gather-sum over 81 views (v5) --------------
// Split by var: block (co, b, var) owns ONE slab and its dd-range
// (var0 -> dd 0..4, var1 -> dd 5..8). Double-buffered (2 x 25.9 KB),
// one barrier per view. Disjoint out slices -> no atomics.
__global__ __launch_bounds__(576)
void k_gather5(const unsigned short* __restrict__ y, float* __restrict__ out) {
    __shared__ float lds[2][SLABSZ];   // 51,840 B
    const int co = blockIdx.x, b = blockIdx.y, var = blockIdx.z;
    const int tid = threadIdx.x;

    for (int i = tid; i < 2 * SLABSZ; i += 576) ((float*)lds)[i] = 0.f;

    const bool stg = (tid < 288);
    const int e0   = (tid % 288) * 8;
    const int srow = e0 / 48, scol = e0 % 48;
    const int ldst = (16 + srow) * SLABW + 16 + scol;
    const unsigned short* ybase =
        y + ((size_t)(var * 64 + co)) * NTOT + (size_t)b * NSPAT + e0;

    const int hh = tid / 12;          // 0..47
    const int w0 = (tid % 12) * 4;    // 0..44
    const int center = (16 + hh) * SLABW + 16 + w0;
    const int kmax = var ? 4 : 5;     // uniform per block

    float acc[5][4] = {};

    uint4 pre0, pre1;
    if (stg) {
        pre0 = *reinterpret_cast<const uint4*>(ybase);                        // uv=0
        pre1 = *reinterpret_cast<const uint4*>(ybase + (size_t)128 * NTOT);   // uv=1
    }
    __syncthreads();   // zero-fill done

    for (int uv = 0; uv < NVIEW; ++uv) {
        float* slab = lds[uv & 1];
        if (stg) {
            float4 lo, hi;
            lo.x = __uint_as_float(pre0.x << 16);
            lo.y = __uint_as_float(pre0.x & 0xffff0000u);
            lo.z = __uint_as_float(pre0.y << 16);
            lo.w = __uint_as_float(pre0.y & 0xffff0000u);
            hi.x = __uint_as_float(pre0.z << 16);
            hi.y = __uint_as_float(pre0.z & 0xffff0000u);
            hi.z = __uint_as_float(pre0.w << 16);
            hi.w = __uint_as_float(pre0.w & 0xffff0000u);
            *reinterpret_cast<float4*>(&slab[ldst])     = lo;
            *reinterpret_cast<float4*>(&slab[ldst + 4]) = hi;
            pre0 = pre1;
            if (uv + 2 < NVIEW)
                pre1 = *reinterpret_cast<const uint4*>(ybase + (size_t)(uv + 2) * 128 * NTOT);
        }
        __syncthreads();   // slab[uv&1] complete; other buffer free to rewrite

        const int uq = uv / 9, vq = uv % 9;
        const int step = (uq - 4) * SLABW + (vq - 4);
#pragma unroll
        for (int k = 0; k < 5; ++k) {
            if (k < kmax) {
                const int mult = var ? (-1 - k) : (4 - k);
                const float* p = &slab[center + mult * step];
                acc[k][0] += p[0];
                acc[k][1] += p[1];
                acc[k][2] += p[2];
                acc[k][3] += p[3];
            }
        }
        // no second barrier: next view writes the OTHER buffer; this one is
        // rewritten only at uv+2, after the uv+1 barrier.
    }

    const int ddb = var ? 5 : 0;
    const size_t ob = ((size_t)(b * 64 + co) * 9 + ddb) * NSPAT + tid * 4;
#pragma unroll
    for (int k = 0; k < 5; ++k) {
        if (k < kmax) {
            float4 o;
            o.x = acc[k][0]; o.y = acc[k][1]; o.z = acc[k][2]; o.w = acc[k][3];
            *reinterpret_cast<float4*>(&out[ob + (size_t)k * NSPAT]) = o;
        }
    }
}

// ---------------- fallback: round-1 direct conv (used if ws too small) -------
__global__ __launch_bounds__(192)
void cost_volume_direct(const float* __restrict__ x,
                        const float* __restrict__ w,
                        float* __restrict__ out) {
    const int ow      = threadIdx.x;
    const int oh      = blockIdx.y * 4 + threadIdx.y;
    const int co_tile = blockIdx.x & 7;
    const int dd      = blockIdx.x >> 3;
    const int b       = blockIdx.z;
    const int d       = dd - 4;
    const int co0     = co_tile * 8;

    int dilat, pad;
    if (d < 0)       { dilat = (-d) * ANG + 1; pad = 36 * (-d); }
    else if (d == 0) { dilat = 1;              pad = 0; }
    else             { dilat = d * ANG - 1;    pad = 36 * d - (ANG - 1); }

    const int ih0 = oh * ANG - pad;
    const int iw0 = ow * ANG - pad;

    float acc[8];
#pragma unroll
    for (int i = 0; i < 8; ++i) acc[i] = 0.f;

    const float* xb = x + (size_t)b * CIN * IMG * IMG;
    for (int kh = 0; kh < ANG; ++kh) {
        const int ih = ih0 + kh * dilat;
        if ((unsigned)ih >= (unsigned)IMG) continue;
        const float* xrow_base = xb + (size_t)ih * IMG;
        const float* wrow      = w + kh * ANG;
        for (int ci = 0; ci < CIN; ++ci) {
            const float* xrow = xrow_base + (size_t)ci * (IMG * IMG);
            float xv[ANG];
#pragma unroll
            for (int kw = 0; kw < ANG; ++kw) {
                const int iw  = iw0 + kw * dilat;
                const bool ok = ((unsigned)iw < (unsigned)IMG);
                const float vv = xrow[ok ? iw : 0];
                xv[kw] = ok ? vv : 0.f;
            }
            const float* wc = wrow + ci * (ANG * ANG);
#pragma unroll
            for (int i = 0; i < 8; ++i) {
                const float* wi = wc + (size_t)(co0 + i) * (CIN * ANG * ANG);
#pragma unroll
                for (int kw = 0; kw < ANG; ++kw)
                    acc[i] = fmaf(xv[kw], wi[kw], acc[i]);
            }
        }
    }
#pragma unroll
    for (int i = 0; i < 8; ++i) {
        const size_t o = ((((size_t)b * COUT + (co0 + i)) * ND + dd) * OHW + oh) * OHW + ow;
        out[o] = acc[i];
    }
}

extern "C" void kernel_launch(void* const* d_in, const int* in_sizes, int n_in,
                              void* d_out, int out_size, void* d_ws, size_t ws_size,
                              hipStream_t stream) {
    const float* x   = (const float*)d_in[0];
    const float* w   = (const float*)d_in[1];
    float*       out = (float*)d_out;

    const size_t AW_BYTES = (size_t)NVIEW * 128 * 64 * 2;        //   1,327,104
    const size_t Y_BYTES  = (size_t)NVIEW * 128 * NTOT * 2;      // 191,102,976
    const size_t NEED     = AW_BYTES + Y_BYTES;                  // ~192.4 MB

    if (ws_size >= NEED) {
        unsigned short* aw = (unsigned short*)d_ws;
        unsigned short* yb = (unsigned short*)((char*)d_ws + AW_BYTES);

        k_wpack  <<<dim3((NVIEW * 128 * 64 + 255) / 256), dim3(256), 0, stream>>>(w, aw);
        k_fused  <<<dim3(OHW, ANG, NB), dim3(512), 0, stream>>>(x, aw, yb);
        k_gather5<<<dim3(COUT, NB, 2), dim3(576), 0, stream>>>(yb, out);
    } else {
        dim3 grid(8 * ND, OHW / 4, NB);
        dim3 block(OHW, 4, 1);
        cost_volume_direct<<<grid, block, 0, stream>>>(x, w, out);
    }
}